// Round 4
// baseline (52.049 us; speedup 1.0000x reference)
//
#include <hip/hip_runtime.h>
#include <math.h>

#define NVOX (2 * 128 * 128 * 128)   // 4,194,304
#define KS 13
#define KR 6
#define LROWS 44                      // 32 output rows + 2*6 halo

__device__ __forceinline__ float4 LD4(const float* p) {
    return *reinterpret_cast<const float4*>(p);
}

// Per-thread normalized Gaussian weights (sigma = clip(scale, 0.1, 10)).
__device__ __forceinline__ void make_weights(float scale, float* wv) {
    float sig = fminf(fmaxf(scale, 0.1f), 10.0f);
    float inv2s2 = -1.0f / (2.0f * sig * sig);
    float sum = 0.f;
#pragma unroll
    for (int t = 0; t < KS; ++t) {
        float d = (float)(t - KR);
        wv[t] = __expf(d * d * inv2s2);
        sum += wv[t];
    }
    float r = 1.0f / sum;
#pragma unroll
    for (int t = 0; t < KS; ++t) wv[t] *= r;
}

// ---------------------------------------------------------------------------
// 1) Fused W+H blur, 4 blocks per (b,d) slice (h-quarters + 6-row halo).
//    Phase A: 16 w-outputs per slot from 9 float4 loads (load-issue cut).
//    XCD swizzle: XCD k owns a contiguous 32-plane d-slab (nwg=1024).
// ---------------------------------------------------------------------------
__global__ __launch_bounds__(256) void wh_blur_kernel(const float* __restrict__ in,
                                                      float* __restrict__ out,
                                                      const float* __restrict__ scale_p) {
    __shared__ float T[LROWS * 128];      // 22.5 KB
    const int i = blockIdx.x;
    const int wid = ((i & 7) << 7) | (i >> 3);   // bijective, nwg=1024
    const int slice = wid >> 2;           // b*128 + d
    const int h0 = (wid & 3) << 5;        // 0/32/64/96
    const float* sp = in + (slice << 14);
    float* op = out + (slice << 14);

    float wv[KS];
    make_weights(scale_p[0], wv);

    // ---- Phase A: W-blur rows h0-6 .. h0+37 (clamped) into T[0..43] ----
    // 352 slots; slot = (row lr, 16-wide w-segment wseg).
    for (int it = 0; it < 2; ++it) {
        int g = threadIdx.x + (it << 8);
        if (g < LROWS * 8) {
            int wseg = g & 7;
            int w0 = wseg << 4;
            int lr = g >> 3;
            int r = h0 - 6 + lr;
            r = r < 0 ? 0 : (r > 127 ? 127 : r);
            const float* rp = sp + (r << 7);

            float F[36];                  // F[i] = row[w0-8+i]; taps F[k+2..k+14]
            if (wseg >= 1 && wseg <= 6) {
#pragma unroll
                for (int i2 = 0; i2 < 9; ++i2) {
                    float4 q = LD4(rp + w0 - 8 + (i2 << 2));
                    F[4 * i2] = q.x; F[4 * i2 + 1] = q.y;
                    F[4 * i2 + 2] = q.z; F[4 * i2 + 3] = q.w;
                }
            } else if (wseg == 0) {       // w0 = 0: F[0..7] clamp to rp[0]
                float e = rp[0];
#pragma unroll
                for (int i2 = 0; i2 < 8; ++i2) F[i2] = e;
#pragma unroll
                for (int i2 = 0; i2 < 7; ++i2) {
                    float4 q = LD4(rp + (i2 << 2));
                    F[8 + 4 * i2] = q.x; F[9 + 4 * i2] = q.y;
                    F[10 + 4 * i2] = q.z; F[11 + 4 * i2] = q.w;
                }
            } else {                      // wseg = 7, w0 = 112: F[24..35] clamp
                float e = rp[127];
#pragma unroll
                for (int i2 = 0; i2 < 6; ++i2) {
                    float4 q = LD4(rp + 104 + (i2 << 2));
                    F[4 * i2] = q.x; F[4 * i2 + 1] = q.y;
                    F[4 * i2 + 2] = q.z; F[4 * i2 + 3] = q.w;
                }
#pragma unroll
                for (int i2 = 24; i2 < 36; ++i2) F[i2] = e;
            }

            float a[16];
#pragma unroll
            for (int k = 0; k < 16; ++k) a[k] = 0.f;
#pragma unroll
            for (int t = 0; t < KS; ++t) {
                float wt = wv[t];
#pragma unroll
                for (int k = 0; k < 16; ++k) a[k] = fmaf(wt, F[k + 2 + t], a[k]);
            }
#pragma unroll
            for (int k = 0; k < 4; ++k)
                *reinterpret_cast<float4*>(&T[(lr << 7) + w0 + (k << 2)]) =
                    make_float4(a[4 * k], a[4 * k + 1], a[4 * k + 2], a[4 * k + 3]);
        }
    }
    __syncthreads();

    // ---- Phase B: H-blur 32 output rows (8 strips of 4 rows) ----
    {
        const int w0 = (threadIdx.x & 31) << 2;
        const int r0 = (threadIdx.x >> 5) << 2;

        float4 win[KS];
#pragma unroll
        for (int t = 0; t < KS; ++t) win[t] = LD4(&T[((r0 + t) << 7) + w0]);
#pragma unroll
        for (int s = 0; s < 4; ++s) {
            float4 acc = make_float4(0.f, 0.f, 0.f, 0.f);
#pragma unroll
            for (int t = 0; t < KS; ++t) {
                float4 v = win[(s + t) % KS];
                float wt = wv[t];
                acc.x = fmaf(wt, v.x, acc.x);
                acc.y = fmaf(wt, v.y, acc.y);
                acc.z = fmaf(wt, v.z, acc.z);
                acc.w = fmaf(wt, v.w, acc.w);
            }
            *reinterpret_cast<float4*>(op + ((h0 + r0 + s) << 7) + w0) = acc;
            int nl = r0 + s + 13;
            nl = nl > LROWS - 1 ? LROWS - 1 : nl;   // s=3 load unused, keep in-range
            win[s % KS] = LD4(&T[(nl << 7) + w0]);
        }
    }
}

// ---------------------------------------------------------------------------
// 2) D-blur, register sliding window, d-chunk of 8 (512 blocks).
//    XCD swizzle aligned with wh_blur's d-slabs (nwg=512).
// ---------------------------------------------------------------------------
__global__ __launch_bounds__(256) void dblur_kernel(const float* __restrict__ in,
                                                    float* __restrict__ out,
                                                    const float* __restrict__ scale_p) {
    const int i = blockIdx.x;
    const int wid = ((i & 7) << 6) | (i >> 3);   // bijective, nwg=512
    const int t0 = wid * 256 + threadIdx.x;      // 0..131071
    const int w0 = (t0 & 31) << 2;
    const int h  = (t0 >> 5) & 127;
    const int d0 = ((t0 >> 12) & 15) << 3;       // 16 chunks of 8
    const int b  = t0 >> 16;
    const int base = (b << 21) | (h << 7) | w0;

    float wv[KS];
    make_weights(scale_p[0], wv);

    float4 win[KS];
#pragma unroll
    for (int t = 0; t < KS; ++t) {
        int r = d0 - 6 + t;
        r = r < 0 ? 0 : (r > 127 ? 127 : r);     // d0 max=120 -> d0+6 ok, keep both
        win[t] = LD4(in + base + (r << 14));
    }
#pragma unroll
    for (int s = 0; s < 8; ++s) {
        float4 acc = make_float4(0.f, 0.f, 0.f, 0.f);
#pragma unroll
        for (int t = 0; t < KS; ++t) {
            float4 v = win[(s + t) % KS];
            float wt = wv[t];
            acc.x = fmaf(wt, v.x, acc.x);
            acc.y = fmaf(wt, v.y, acc.y);
            acc.z = fmaf(wt, v.z, acc.z);
            acc.w = fmaf(wt, v.w, acc.w);
        }
        *reinterpret_cast<float4*>(out + base + ((d0 + s) << 14)) = acc;
        int rn = d0 + s + 7;
        rn = rn > 127 ? 127 : rn;
        win[s % KS] = LD4(in + base + (rn << 14));
    }
}

// ---------------------------------------------------------------------------
// 3) Hessian + MLP, h-sliding register window + shuffle w-neighbors,
//    h-chunk of 8 (512 blocks). scale folded into b1 (launch-constant).
//    XCD swizzle aligned with dblur's d-slabs (nwg=512). Scalar MLP.
// ---------------------------------------------------------------------------
__device__ __forceinline__ void lohi(int c, int& lo, int& hi, float& s) {
    lo = c > 0 ? c - 1 : 0;
    hi = c < 127 ? c + 1 : 127;
    s = 1.0f / (float)(hi - lo);
}

__device__ __forceinline__ int CH(int v) {
    return v < 0 ? 0 : (v > 127 ? 127 : v);
}

__global__ __launch_bounds__(256) void hess_mlp_kernel(const float* __restrict__ S,
                                const float* __restrict__ scale_p,
                                const float* __restrict__ W1, const float* __restrict__ b1,
                                const float* __restrict__ W2, const float* __restrict__ b2,
                                float* __restrict__ out) {
    const int i = blockIdx.x;
    const int wid = ((i & 7) << 6) | (i >> 3);   // bijective, nwg=512
    const int t = wid * 256 + threadIdx.x;       // 0..131071
    const int l = t & 31;
    const int w0 = l << 2;
    const int hb = ((t >> 5) & 15) << 3;         // h-strip base (8 rows)
    const int d = (t >> 9) & 127;
    const int b = t >> 16;
    const int lane = threadIdx.x & 63;
    const bool l0 = (l == 0), l31 = (l == 31);

    int ld, hd; float sd; lohi(d, ld, hd, sd);
    int ti, tj; float s_hd, s_ld;
    lohi(hd, ti, tj, s_hd); lohi(ld, ti, tj, s_ld);
    const bool d_top = (d == 127), d_bot = (d == 0);
    const int dp2 = d > 125 ? 127 : d + 2;
    const int dm2 = d < 2 ? 0 : d - 2;

    float sw[4], s_hw[4], s_lw[4];
#pragma unroll
    for (int j = 0; j < 4; ++j) {
        int lw, hw; lohi(w0 + j, lw, hw, sw[j]);
        lohi(hw, ti, tj, s_hw[j]); lohi(lw, ti, tj, s_lw[j]);
    }

    const float scale = scale_p[0];
    // Fold the constant 7th feature (scale) into the bias: saves 10 FMA/voxel.
    float b1e[10];
#pragma unroll
    for (int u = 0; u < 10; ++u) b1e[u] = fmaf(scale, W1[u * 7 + 6], b1[u]);

    const float* base = S + (b << 21) + w0;
    auto RP = [&](int dd, int hh) { return base + (dd << 14) + (hh << 7); };
    float* obase = out + (b << 21) + (d << 14) + w0;

    float4 nd0 = LD4(RP(d, CH(hb - 2))), nd1 = LD4(RP(d, CH(hb - 1))),
           nd2 = LD4(RP(d, hb)),        nd3 = LD4(RP(d, hb + 1)),
           nd4 = LD4(RP(d, hb + 2));
    float4 pm0 = LD4(RP(ld, CH(hb - 1))), pm1 = LD4(RP(ld, hb)), pm2 = LD4(RP(ld, hb + 1));
    float4 pp0 = LD4(RP(hd, CH(hb - 1))), pp1 = LD4(RP(hd, hb)), pp2 = LD4(RP(hd, hb + 1));

#pragma unroll
    for (int s = 0; s < 8; ++s) {
        const int h = hb + s;
        const float4 qp = LD4(RP(dp2, h));
        const float4 qm = LD4(RP(dm2, h));

        int lh, hh; float sh; lohi(h, lh, hh, sh);
        float s_hh, s_lh; lohi(hh, ti, tj, s_hh); lohi(lh, ti, tj, s_lh);
        const bool h_top = (h == 127), h_bot = (h == 0);

        float c_lz = __shfl(nd2.z, lane - 1), c_lw = __shfl(nd2.w, lane - 1);
        float c_rx = __shfl(nd2.x, lane + 1), c_ry = __shfl(nd2.y, lane + 1);
        float r1_lw = __shfl(nd1.w, lane - 1), r1_rx = __shfl(nd1.x, lane + 1);
        float r3_lw = __shfl(nd3.w, lane - 1), r3_rx = __shfl(nd3.x, lane + 1);
        float pmlw = __shfl(pm1.w, lane - 1), pmrx = __shfl(pm1.x, lane + 1);
        float pplw = __shfl(pp1.w, lane - 1), pprx = __shfl(pp1.x, lane + 1);

        const float va[4]  = {nd2.x, nd2.y, nd2.z, nd2.w};
        const float n0a[4] = {nd0.x, nd0.y, nd0.z, nd0.w};
        const float n1a[4] = {nd1.x, nd1.y, nd1.z, nd1.w};
        const float n3a[4] = {nd3.x, nd3.y, nd3.z, nd3.w};
        const float n4a[4] = {nd4.x, nd4.y, nd4.z, nd4.w};
        const float pm0a[4] = {pm0.x, pm0.y, pm0.z, pm0.w};
        const float pm1a[4] = {pm1.x, pm1.y, pm1.z, pm1.w};
        const float pm2a[4] = {pm2.x, pm2.y, pm2.z, pm2.w};
        const float pp0a[4] = {pp0.x, pp0.y, pp0.z, pp0.w};
        const float pp1a[4] = {pp1.x, pp1.y, pp1.z, pp1.w};
        const float pp2a[4] = {pp2.x, pp2.y, pp2.z, pp2.w};
        const float qpa[4] = {qp.x, qp.y, qp.z, qp.w};
        const float qma[4] = {qm.x, qm.y, qm.z, qm.w};

        const float c_m1[4] = {l0 ? va[0] : c_lw, va[0], va[1], va[2]};
        const float c_p1[4] = {va[1], va[2], va[3], l31 ? va[3] : c_rx};
        const float c_m2[4] = {l0 ? va[0] : c_lz, l0 ? va[0] : c_lw, va[0], va[1]};
        const float c_p2[4] = {va[2], va[3], l31 ? va[3] : c_rx, l31 ? va[3] : c_ry};
        const float r1m[4] = {l0 ? n1a[0] : r1_lw, n1a[0], n1a[1], n1a[2]};
        const float r1p[4] = {n1a[1], n1a[2], n1a[3], l31 ? n1a[3] : r1_rx};
        const float r3m[4] = {l0 ? n3a[0] : r3_lw, n3a[0], n3a[1], n3a[2]};
        const float r3p[4] = {n3a[1], n3a[2], n3a[3], l31 ? n3a[3] : r3_rx};
        const float pmm[4] = {l0 ? pm1a[0] : pmlw, pm1a[0], pm1a[1], pm1a[2]};
        const float pmp[4] = {pm1a[1], pm1a[2], pm1a[3], l31 ? pm1a[3] : pmrx};
        const float ppm[4] = {l0 ? pp1a[0] : pplw, pp1a[0], pp1a[1], pp1a[2]};
        const float ppp[4] = {pp1a[1], pp1a[2], pp1a[3], l31 ? pp1a[3] : pprx};

        float ov[4];
#pragma unroll
        for (int j = 0; j < 4; ++j) {
            const float fDD = sd * (s_hd * (qpa[j] - (d_top ? pm1a[j] : va[j]))
                                  - s_ld * ((d_bot ? pp1a[j] : va[j]) - qma[j]));
            const float fHH = sh * (s_hh * (n4a[j] - (h_top ? n1a[j] : va[j]))
                                  - s_lh * ((h_bot ? n3a[j] : va[j]) - n0a[j]));
            const float fDH = sd * sh * ((pp2a[j] - pp0a[j]) - (pm2a[j] - pm0a[j]));
            const float fHW = sh * sw[j] * ((r3p[j] - r3m[j]) - (r1p[j] - r1m[j]));
            const float fDW = sd * sw[j] * ((ppp[j] - ppm[j]) - (pmp[j] - pmm[j]));
            const float Aw = (j == 3 && l31) ? c_m1[j] : va[j];
            const float Bw = (j == 0 && l0) ? c_p1[j] : va[j];
            const float fWW = sw[j] * (s_hw[j] * (c_p2[j] - Aw) - s_lw[j] * (Bw - c_m2[j]));

            const float ft[6] = {fDD, fDH, fDW, fHH, fHW, fWW};
            float o = b2[0];
#pragma unroll
            for (int u = 0; u < 10; ++u) {
                float a = b1e[u];
#pragma unroll
                for (int k = 0; k < 6; ++k) a = fmaf(ft[k], W1[u * 7 + k], a);
                a = fmaxf(a, 0.f);
                o = fmaf(a, W2[u], o);
            }
            float e = __expf(-o);
            ov[j] = __builtin_amdgcn_rcpf(1.0f + e);
        }
        *reinterpret_cast<float4*>(obase + (h << 7)) = make_float4(ov[0], ov[1], ov[2], ov[3]);

        nd0 = nd1; nd1 = nd2; nd2 = nd3; nd3 = nd4;
        nd4 = LD4(RP(d, CH(h + 3)));
        pm0 = pm1; pm1 = pm2; pm2 = LD4(RP(ld, CH(h + 2)));
        pp0 = pp1; pp1 = pp2; pp2 = LD4(RP(hd, CH(h + 2)));
    }
}

// ---------------------------------------------------------------------------
extern "C" void kernel_launch(void* const* d_in, const int* in_sizes, int n_in,
                              void* d_out, int out_size, void* d_ws, size_t ws_size,
                              hipStream_t stream) {
    const float* x     = (const float*)d_in[0];
    const float* scale = (const float*)d_in[1];
    const float* W1    = (const float*)d_in[2];
    const float* b1    = (const float*)d_in[3];
    const float* W2    = (const float*)d_in[4];
    const float* b2    = (const float*)d_in[5];
    float* out = (float*)d_out;

    float* ws0 = (float*)d_ws;            // S volume (16 MB)
    float* ws1 = ws0 + NVOX;              // W+H-blurred volume (16 MB)

    wh_blur_kernel<<<2 * 128 * 4, 256, 0, stream>>>(x, ws1, scale);        // W+H
    dblur_kernel<<<NVOX / 32 / 256, 256, 0, stream>>>(ws1, ws0, scale);    // D (chunk 8)
    hess_mlp_kernel<<<NVOX / 32 / 256, 256, 0, stream>>>(ws0, scale, W1, b1, W2, b2, out);
}

// Round 5
// 44.362 us; speedup vs baseline: 1.1733x; 1.1733x over previous
//
#include <hip/hip_runtime.h>
#include <math.h>

#define NVOX (2 * 128 * 128 * 128)   // 4,194,304
#define KS 13
#define KR 6
#define LROWS 44                      // 32 output rows + 2*6 halo

__device__ __forceinline__ float4 LD4(const float* p) {
    return *reinterpret_cast<const float4*>(p);
}

// Per-thread normalized Gaussian weights (sigma = clip(scale, 0.1, 10)).
__device__ __forceinline__ void make_weights(float scale, float* wv) {
    float sig = fminf(fmaxf(scale, 0.1f), 10.0f);
    float inv2s2 = -1.0f / (2.0f * sig * sig);
    float sum = 0.f;
#pragma unroll
    for (int t = 0; t < KS; ++t) {
        float d = (float)(t - KR);
        wv[t] = __expf(d * d * inv2s2);
        sum += wv[t];
    }
    float r = 1.0f / sum;
#pragma unroll
    for (int t = 0; t < KS; ++t) wv[t] *= r;
}

// ---------------------------------------------------------------------------
// 1) Fused W+H blur, 4 blocks per (b,d) slice (h-quarters + 6-row halo).
//    Phase A: 8 w-outputs per slot, all-vector loads (interior 6x f4,
//    edges 4x f4 + clamp-broadcast). XCD swizzle (nwg=1024).
// ---------------------------------------------------------------------------
__global__ __launch_bounds__(256) void wh_blur_kernel(const float* __restrict__ in,
                                                      float* __restrict__ out,
                                                      const float* __restrict__ scale_p) {
    __shared__ float T[LROWS * 128];      // 22.5 KB
    const int i = blockIdx.x;
    const int wid = ((i & 7) << 7) | (i >> 3);   // bijective, nwg=1024
    const int slice = wid >> 2;           // b*128 + d
    const int h0 = (wid & 3) << 5;        // 0/32/64/96
    const float* sp = in + (slice << 14);
    float* op = out + (slice << 14);

    float wv[KS];
    make_weights(scale_p[0], wv);

    // ---- Phase A: W-blur rows h0-6 .. h0+37 (clamped) into T[0..43] ----
    // 704 slots; slot = (row lr = g>>4, 8-wide w-segment wseg = g&15).
    for (int it = 0; it < 3; ++it) {
        int g = threadIdx.x + (it << 8);
        if (g < LROWS * 16) {
            int wseg = g & 15;
            int w0 = wseg << 3;
            int lr = g >> 4;
            int r = h0 - 6 + lr;
            r = r < 0 ? 0 : (r > 127 ? 127 : r);
            const float* rp = sp + (r << 7);

            float F[24];                  // F[i] = row[w0-8+i]; taps F[k+2..k+14]
            if (wseg >= 1 && wseg <= 14) {
#pragma unroll
                for (int i2 = 0; i2 < 6; ++i2) {
                    float4 q = LD4(rp + w0 - 8 + (i2 << 2));
                    F[4 * i2] = q.x; F[4 * i2 + 1] = q.y;
                    F[4 * i2 + 2] = q.z; F[4 * i2 + 3] = q.w;
                }
            } else if (wseg == 0) {       // w0 = 0: F[0..7] clamp to rp[0]
                float e = rp[0];
#pragma unroll
                for (int i2 = 0; i2 < 8; ++i2) F[i2] = e;
#pragma unroll
                for (int i2 = 0; i2 < 4; ++i2) {
                    float4 q = LD4(rp + (i2 << 2));
                    F[8 + 4 * i2] = q.x; F[9 + 4 * i2] = q.y;
                    F[10 + 4 * i2] = q.z; F[11 + 4 * i2] = q.w;
                }
            } else {                      // wseg = 15, w0 = 120: F[16..23] clamp
                float e = rp[127];
#pragma unroll
                for (int i2 = 0; i2 < 4; ++i2) {
                    float4 q = LD4(rp + 112 + (i2 << 2));
                    F[4 * i2] = q.x; F[4 * i2 + 1] = q.y;
                    F[4 * i2 + 2] = q.z; F[4 * i2 + 3] = q.w;
                }
#pragma unroll
                for (int i2 = 16; i2 < 24; ++i2) F[i2] = e;
            }

            float a[8];
#pragma unroll
            for (int k = 0; k < 8; ++k) a[k] = 0.f;
#pragma unroll
            for (int t = 0; t < KS; ++t) {
                float wt = wv[t];
#pragma unroll
                for (int k = 0; k < 8; ++k) a[k] = fmaf(wt, F[k + 2 + t], a[k]);
            }
            *reinterpret_cast<float4*>(&T[(lr << 7) + w0]) =
                make_float4(a[0], a[1], a[2], a[3]);
            *reinterpret_cast<float4*>(&T[(lr << 7) + w0 + 4]) =
                make_float4(a[4], a[5], a[6], a[7]);
        }
    }
    __syncthreads();

    // ---- Phase B: H-blur 32 output rows (8 strips of 4 rows) ----
    {
        const int w0 = (threadIdx.x & 31) << 2;
        const int r0 = (threadIdx.x >> 5) << 2;

        float4 win[KS];
#pragma unroll
        for (int t = 0; t < KS; ++t) win[t] = LD4(&T[((r0 + t) << 7) + w0]);
#pragma unroll
        for (int s = 0; s < 4; ++s) {
            float4 acc = make_float4(0.f, 0.f, 0.f, 0.f);
#pragma unroll
            for (int t = 0; t < KS; ++t) {
                float4 v = win[(s + t) % KS];
                float wt = wv[t];
                acc.x = fmaf(wt, v.x, acc.x);
                acc.y = fmaf(wt, v.y, acc.y);
                acc.z = fmaf(wt, v.z, acc.z);
                acc.w = fmaf(wt, v.w, acc.w);
            }
            *reinterpret_cast<float4*>(op + ((h0 + r0 + s) << 7) + w0) = acc;
            int nl = r0 + s + 13;
            nl = nl > LROWS - 1 ? LROWS - 1 : nl;   // s=3 load unused, keep in-range
            win[s % KS] = LD4(&T[(nl << 7) + w0]);
        }
    }
}

// ---------------------------------------------------------------------------
// 2) D-blur, register sliding window, d-chunk of 8 (512 blocks).
//    XCD swizzle aligned with wh_blur's d-slabs (nwg=512).
// ---------------------------------------------------------------------------
__global__ __launch_bounds__(256) void dblur_kernel(const float* __restrict__ in,
                                                    float* __restrict__ out,
                                                    const float* __restrict__ scale_p) {
    const int i = blockIdx.x;
    const int wid = ((i & 7) << 6) | (i >> 3);   // bijective, nwg=512
    const int t0 = wid * 256 + threadIdx.x;      // 0..131071
    const int w0 = (t0 & 31) << 2;
    const int h  = (t0 >> 5) & 127;
    const int d0 = ((t0 >> 12) & 15) << 3;       // 16 chunks of 8
    const int b  = t0 >> 16;
    const int base = (b << 21) | (h << 7) | w0;

    float wv[KS];
    make_weights(scale_p[0], wv);

    float4 win[KS];
#pragma unroll
    for (int t = 0; t < KS; ++t) {
        int r = d0 - 6 + t;
        r = r < 0 ? 0 : (r > 127 ? 127 : r);     // d0 max=120 -> d0+6 ok, keep both
        win[t] = LD4(in + base + (r << 14));
    }
#pragma unroll
    for (int s = 0; s < 8; ++s) {
        float4 acc = make_float4(0.f, 0.f, 0.f, 0.f);
#pragma unroll
        for (int t = 0; t < KS; ++t) {
            float4 v = win[(s + t) % KS];
            float wt = wv[t];
            acc.x = fmaf(wt, v.x, acc.x);
            acc.y = fmaf(wt, v.y, acc.y);
            acc.z = fmaf(wt, v.z, acc.z);
            acc.w = fmaf(wt, v.w, acc.w);
        }
        *reinterpret_cast<float4*>(out + base + ((d0 + s) << 14)) = acc;
        int rn = d0 + s + 7;
        rn = rn > 127 ? 127 : rn;
        win[s % KS] = LD4(in + base + (rn << 14));
    }
}

// ---------------------------------------------------------------------------
// 3) Hessian + MLP, h-sliding register window + shuffle w-neighbors,
//    h-chunk of 4 (1024 blocks). scale folded into b1 (launch-constant).
//    XCD swizzle aligned with dblur's d-slabs (nwg=1024). Scalar MLP.
// ---------------------------------------------------------------------------
__device__ __forceinline__ void lohi(int c, int& lo, int& hi, float& s) {
    lo = c > 0 ? c - 1 : 0;
    hi = c < 127 ? c + 1 : 127;
    s = 1.0f / (float)(hi - lo);
}

__device__ __forceinline__ int CH(int v) {
    return v < 0 ? 0 : (v > 127 ? 127 : v);
}

__global__ __launch_bounds__(256) void hess_mlp_kernel(const float* __restrict__ S,
                                const float* __restrict__ scale_p,
                                const float* __restrict__ W1, const float* __restrict__ b1,
                                const float* __restrict__ W2, const float* __restrict__ b2,
                                float* __restrict__ out) {
    const int i = blockIdx.x;
    const int wid = ((i & 7) << 7) | (i >> 3);   // bijective, nwg=1024
    const int t = wid * 256 + threadIdx.x;       // 0..262143
    const int l = t & 31;
    const int w0 = l << 2;
    const int hb = ((t >> 5) & 31) << 2;         // h-strip base (4 rows)
    const int d = (t >> 10) & 127;
    const int b = t >> 17;
    const int lane = threadIdx.x & 63;
    const bool l0 = (l == 0), l31 = (l == 31);

    int ld, hd; float sd; lohi(d, ld, hd, sd);
    int ti, tj; float s_hd, s_ld;
    lohi(hd, ti, tj, s_hd); lohi(ld, ti, tj, s_ld);
    const bool d_top = (d == 127), d_bot = (d == 0);
    const int dp2 = d > 125 ? 127 : d + 2;
    const int dm2 = d < 2 ? 0 : d - 2;

    float sw[4], s_hw[4], s_lw[4];
#pragma unroll
    for (int j = 0; j < 4; ++j) {
        int lw, hw; lohi(w0 + j, lw, hw, sw[j]);
        lohi(hw, ti, tj, s_hw[j]); lohi(lw, ti, tj, s_lw[j]);
    }

    const float scale = scale_p[0];
    // Fold the constant 7th feature (scale) into the bias: saves 10 FMA/voxel.
    float b1e[10];
#pragma unroll
    for (int u = 0; u < 10; ++u) b1e[u] = fmaf(scale, W1[u * 7 + 6], b1[u]);

    const float* base = S + (b << 21) + w0;
    auto RP = [&](int dd, int hh) { return base + (dd << 14) + (hh << 7); };
    float* obase = out + (b << 21) + (d << 14) + w0;

    float4 nd0 = LD4(RP(d, CH(hb - 2))), nd1 = LD4(RP(d, CH(hb - 1))),
           nd2 = LD4(RP(d, hb)),        nd3 = LD4(RP(d, hb + 1)),
           nd4 = LD4(RP(d, CH(hb + 2)));
    float4 pm0 = LD4(RP(ld, CH(hb - 1))), pm1 = LD4(RP(ld, hb)), pm2 = LD4(RP(ld, hb + 1));
    float4 pp0 = LD4(RP(hd, CH(hb - 1))), pp1 = LD4(RP(hd, hb)), pp2 = LD4(RP(hd, hb + 1));

#pragma unroll
    for (int s = 0; s < 4; ++s) {
        const int h = hb + s;
        const float4 qp = LD4(RP(dp2, h));
        const float4 qm = LD4(RP(dm2, h));

        int lh, hh; float sh; lohi(h, lh, hh, sh);
        float s_hh, s_lh; lohi(hh, ti, tj, s_hh); lohi(lh, ti, tj, s_lh);
        const bool h_top = (h == 127), h_bot = (h == 0);

        float c_lz = __shfl(nd2.z, lane - 1), c_lw = __shfl(nd2.w, lane - 1);
        float c_rx = __shfl(nd2.x, lane + 1), c_ry = __shfl(nd2.y, lane + 1);
        float r1_lw = __shfl(nd1.w, lane - 1), r1_rx = __shfl(nd1.x, lane + 1);
        float r3_lw = __shfl(nd3.w, lane - 1), r3_rx = __shfl(nd3.x, lane + 1);
        float pmlw = __shfl(pm1.w, lane - 1), pmrx = __shfl(pm1.x, lane + 1);
        float pplw = __shfl(pp1.w, lane - 1), pprx = __shfl(pp1.x, lane + 1);

        const float va[4]  = {nd2.x, nd2.y, nd2.z, nd2.w};
        const float n0a[4] = {nd0.x, nd0.y, nd0.z, nd0.w};
        const float n1a[4] = {nd1.x, nd1.y, nd1.z, nd1.w};
        const float n3a[4] = {nd3.x, nd3.y, nd3.z, nd3.w};
        const float n4a[4] = {nd4.x, nd4.y, nd4.z, nd4.w};
        const float pm0a[4] = {pm0.x, pm0.y, pm0.z, pm0.w};
        const float pm1a[4] = {pm1.x, pm1.y, pm1.z, pm1.w};
        const float pm2a[4] = {pm2.x, pm2.y, pm2.z, pm2.w};
        const float pp0a[4] = {pp0.x, pp0.y, pp0.z, pp0.w};
        const float pp1a[4] = {pp1.x, pp1.y, pp1.z, pp1.w};
        const float pp2a[4] = {pp2.x, pp2.y, pp2.z, pp2.w};
        const float qpa[4] = {qp.x, qp.y, qp.z, qp.w};
        const float qma[4] = {qm.x, qm.y, qm.z, qm.w};

        const float c_m1[4] = {l0 ? va[0] : c_lw, va[0], va[1], va[2]};
        const float c_p1[4] = {va[1], va[2], va[3], l31 ? va[3] : c_rx};
        const float c_m2[4] = {l0 ? va[0] : c_lz, l0 ? va[0] : c_lw, va[0], va[1]};
        const float c_p2[4] = {va[2], va[3], l31 ? va[3] : c_rx, l31 ? va[3] : c_ry};
        const float r1m[4] = {l0 ? n1a[0] : r1_lw, n1a[0], n1a[1], n1a[2]};
        const float r1p[4] = {n1a[1], n1a[2], n1a[3], l31 ? n1a[3] : r1_rx};
        const float r3m[4] = {l0 ? n3a[0] : r3_lw, n3a[0], n3a[1], n3a[2]};
        const float r3p[4] = {n3a[1], n3a[2], n3a[3], l31 ? n3a[3] : r3_rx};
        const float pmm[4] = {l0 ? pm1a[0] : pmlw, pm1a[0], pm1a[1], pm1a[2]};
        const float pmp[4] = {pm1a[1], pm1a[2], pm1a[3], l31 ? pm1a[3] : pmrx};
        const float ppm[4] = {l0 ? pp1a[0] : pplw, pp1a[0], pp1a[1], pp1a[2]};
        const float ppp[4] = {pp1a[1], pp1a[2], pp1a[3], l31 ? pp1a[3] : pprx};

        float ov[4];
#pragma unroll
        for (int j = 0; j < 4; ++j) {
            const float fDD = sd * (s_hd * (qpa[j] - (d_top ? pm1a[j] : va[j]))
                                  - s_ld * ((d_bot ? pp1a[j] : va[j]) - qma[j]));
            const float fHH = sh * (s_hh * (n4a[j] - (h_top ? n1a[j] : va[j]))
                                  - s_lh * ((h_bot ? n3a[j] : va[j]) - n0a[j]));
            const float fDH = sd * sh * ((pp2a[j] - pp0a[j]) - (pm2a[j] - pm0a[j]));
            const float fHW = sh * sw[j] * ((r3p[j] - r3m[j]) - (r1p[j] - r1m[j]));
            const float fDW = sd * sw[j] * ((ppp[j] - ppm[j]) - (pmp[j] - pmm[j]));
            const float Aw = (j == 3 && l31) ? c_m1[j] : va[j];
            const float Bw = (j == 0 && l0) ? c_p1[j] : va[j];
            const float fWW = sw[j] * (s_hw[j] * (c_p2[j] - Aw) - s_lw[j] * (Bw - c_m2[j]));

            const float ft[6] = {fDD, fDH, fDW, fHH, fHW, fWW};
            float o = b2[0];
#pragma unroll
            for (int u = 0; u < 10; ++u) {
                float a = b1e[u];
#pragma unroll
                for (int k = 0; k < 6; ++k) a = fmaf(ft[k], W1[u * 7 + k], a);
                a = fmaxf(a, 0.f);
                o = fmaf(a, W2[u], o);
            }
            float e = __expf(-o);
            ov[j] = __builtin_amdgcn_rcpf(1.0f + e);
        }
        *reinterpret_cast<float4*>(obase + (h << 7)) = make_float4(ov[0], ov[1], ov[2], ov[3]);

        nd0 = nd1; nd1 = nd2; nd2 = nd3; nd3 = nd4;
        nd4 = LD4(RP(d, CH(h + 3)));
        pm0 = pm1; pm1 = pm2; pm2 = LD4(RP(ld, CH(h + 2)));
        pp0 = pp1; pp1 = pp2; pp2 = LD4(RP(hd, CH(h + 2)));
    }
}

// ---------------------------------------------------------------------------
extern "C" void kernel_launch(void* const* d_in, const int* in_sizes, int n_in,
                              void* d_out, int out_size, void* d_ws, size_t ws_size,
                              hipStream_t stream) {
    const float* x     = (const float*)d_in[0];
    const float* scale = (const float*)d_in[1];
    const float* W1    = (const float*)d_in[2];
    const float* b1    = (const float*)d_in[3];
    const float* W2    = (const float*)d_in[4];
    const float* b2    = (const float*)d_in[5];
    float* out = (float*)d_out;

    float* ws0 = (float*)d_ws;            // S volume (16 MB)
    float* ws1 = ws0 + NVOX;              // W+H-blurred volume (16 MB)

    wh_blur_kernel<<<2 * 128 * 4, 256, 0, stream>>>(x, ws1, scale);        // W+H
    dblur_kernel<<<NVOX / 32 / 256, 256, 0, stream>>>(ws1, ws0, scale);    // D (chunk 8)
    hess_mlp_kernel<<<NVOX / 16 / 256, 256, 0, stream>>>(ws0, scale, W1, b1, W2, b2, out);
}